// Round 5
// baseline (210.015 us; speedup 1.0000x reference)
//
#include <hip/hip_runtime.h>

#define GAMMA 0.01f
#define INV_GAMMA 100.0f
#define B 32
#define G 2048
#define C 16
#define S 8
#define L 3
#define M 16
#define NB 256          // 32 b x 8 tiles; == CU count, co-residency by capacity
#define TPB 512
#define TILE 256        // g per block
#define POISON 0xAAAAAAAAu   // harness poisons d_ws; posted maxes are >=0 (sign bit 0)

__device__ __forceinline__ float waveMax(float v) {
#pragma unroll
    for (int off = 32; off > 0; off >>= 1)
        v = fmaxf(v, __shfl_xor(v, off, 64));
    return v;
}

// 512-thread block max, broadcast. Leading guard sync makes repeated use safe.
__device__ __forceinline__ float blockMaxBcast(float v, float* scratch8) {
    float wm = waveMax(v);
    __syncthreads();
    if ((threadIdx.x & 63) == 0) scratch8[threadIdx.x >> 6] = wm;
    __syncthreads();
    float r = fmaxf(fmaxf(scratch8[0], scratch8[1]), fmaxf(scratch8[2], scratch8[3]));
    return fmaxf(r, fmaxf(fmaxf(scratch8[4], scratch8[5]), fmaxf(scratch8[6], scratch8[7])));
}

__device__ __forceinline__ void postSlot(unsigned* slot, float bm) {
    if (threadIdx.x == 0)
        __hip_atomic_store(slot, __float_as_uint(bm),
                           __ATOMIC_RELEASE, __HIP_MEMORY_SCOPE_AGENT);
}

// Flat barrier: threads 256..511 poll one slot each (threads 0..255 may still be
// doing overlapped work when this is called); result = grid max, broadcast.
__device__ __forceinline__ float waitMax(const unsigned* slots, float* scratch8) {
    float v = -INFINITY;
    const int t = threadIdx.x;
    if (t >= TPB - NB) {
        const unsigned* p = &slots[t - (TPB - NB)];
        unsigned u = __hip_atomic_load(p, __ATOMIC_RELAXED, __HIP_MEMORY_SCOPE_AGENT);
        while (u == POISON) {
            __builtin_amdgcn_s_sleep(2);
            u = __hip_atomic_load(p, __ATOMIC_RELAXED, __HIP_MEMORY_SCOPE_AGENT);
        }
        v = __uint_as_float(u);
    }
    return blockMaxBcast(v, scratch8);
}

__global__ __launch_bounds__(TPB, 1) void fused(
    const float* __restrict__ x, const float* __restrict__ W,
    const int* __restrict__ I, float* __restrict__ out,
    unsigned* __restrict__ Slots, float* __restrict__ Ry) {
    __shared__ float Vrow[G];        // 8 KB
    __shared__ float CvL[C][TILE];   // 16 KB, block-local Cv tile
    __shared__ float WsL[M * C];     // 1 KB
    __shared__ float scratch8[8];

    const int t   = threadIdx.x;
    const int blk = blockIdx.x;
    const int b   = blk >> 3;
    const int g0  = (blk & 7) * TILE;

    // Ws = softmax(W, axis=1), redundant per block. First read is after the
    // syncs inside phase A's blockMaxBcast.
    if (t < M * C) {
        int m = t >> 4, c = t & 15;
        float rmax = -INFINITY;
#pragma unroll
        for (int j = 0; j < C; j++) rmax = fmaxf(rmax, W[m * C + j]);
        float rsum = 0.f;
#pragma unroll
        for (int j = 0; j < C; j++) rsum += __expf(W[m * C + j] - rmax);
        WsL[t] = __expf(W[m * C + c] - rmax) / rsum;
    }

    float Rreg = (t < TILE) ? x[(size_t)b * G + g0 + t] : 0.f;  // unscaled y
    float s3 = 1.0f;

    for (int it = 0; it < 5; ++it) {
        // ---- stage V row b into LDS (scaled by s3) ----
        if (it == 0) {
            ((float4*)Vrow)[t] = ((const float4*)(x + (size_t)b * G))[t];  // 8 KB
        } else {
            // agent loads bypass stale per-XCD L2; producers stored agent-scope
#pragma unroll
            for (int k = 0; k < 4; k++) {
                int j = t + k * TPB;
                float v = __hip_atomic_load(&Ry[(size_t)b * G + j],
                                            __ATOMIC_RELAXED, __HIP_MEMORY_SCOPE_AGENT);
                Vrow[j] = s3 * v;
            }
        }
        __syncthreads();

        // ---- Phase A: Cv tile = softor_S(prod_L gather(V)) ----
        const int gl = t & 255;
        const int cb = (t >> 8) * 8;
        float ymax = -INFINITY;
#pragma unroll 2
        for (int cc = 0; cc < 8; cc++) {
            const int c = cb + cc;
            const int4* ip = (const int4*)(I + ((size_t)c * G + g0 + gl) * (S * L));
            int idx[S * L];
#pragma unroll
            for (int q = 0; q < 6; q++) {
                int4 v = ip[q];
                idx[q * 4 + 0] = v.x; idx[q * 4 + 1] = v.y;
                idx[q * 4 + 2] = v.z; idx[q * 4 + 3] = v.w;
            }
            float body[S];
#pragma unroll
            for (int ss = 0; ss < S; ss++)
                body[ss] = Vrow[idx[ss * 3]] * Vrow[idx[ss * 3 + 1]] * Vrow[idx[ss * 3 + 2]];
            float bm = body[0];
#pragma unroll
            for (int ss = 1; ss < S; ss++) bm = fmaxf(bm, body[ss]);
            float sum = 0.f;
#pragma unroll
            for (int ss = 0; ss < S; ss++) sum += __expf((body[ss] - bm) * INV_GAMMA);
            float y = bm + GAMMA * __logf(sum);
            CvL[c][gl] = y;
            ymax = fmaxf(ymax, y);
        }
        float bmA = blockMaxBcast(ymax, scratch8);   // also publishes CvL
        postSlot(&Slots[(it * 3 + 0) * NB + blk], bmA);

        // ---- Phase B part 1 (overlapped with barrier A): Hraw = Ws @ Cv ----
        // Linear in Cv, so it needs no s1. Threads 256..511 poll meanwhile.
        float Hraw[M], hmr = -INFINITY;
        if (t < TILE) {
            float cv[C];
#pragma unroll
            for (int c = 0; c < C; c++) cv[c] = CvL[c][t];
#pragma unroll
            for (int m = 0; m < M; m++) {
                float acc = 0.f;
#pragma unroll
                for (int c = 0; c < C; c++) acc = fmaf(WsL[m * C + c], cv[c], acc);
                Hraw[m] = acc; hmr = fmaxf(hmr, acc);
            }
        }
        float m1 = waitMax(&Slots[(it * 3 + 0) * NB], scratch8);
        float s1 = (m1 > 1.0f) ? 1.0f / m1 : 1.0f;

        // ---- Phase B part 2: Hy = softor_M(s1 * Hraw) ----
        float hy = -INFINITY;
        if (t < TILE) {
            float hm = s1 * hmr;           // s1 > 0: max commutes with scaling
            float sum = 0.f;
#pragma unroll
            for (int m = 0; m < M; m++)
                sum += __expf((s1 * Hraw[m] - hm) * INV_GAMMA);
            hy = hm + GAMMA * __logf(sum);
        }
        float bmB = blockMaxBcast(hy, scratch8);
        postSlot(&Slots[(it * 3 + 1) * NB + blk], bmB);
        float m2 = waitMax(&Slots[(it * 3 + 1) * NB], scratch8);
        float s2 = (m2 > 1.0f) ? 1.0f / m2 : 1.0f;

        // ---- Phase C: R_new = softor_2(s3*R, s2*Hy) ----
        float ynew = -INFINITY;
        if (t < TILE) {
            float Rv = s3 * Rreg;
            float rv = s2 * hy;
            float a = fmaxf(Rv, rv), d = fminf(Rv, rv);
            ynew = a + GAMMA * __logf(1.0f + __expf((d - a) * INV_GAMMA));
            Rreg = ynew;
            if (it < 4)   // agent store -> LLC; drained by the vmcnt(0) at the
                          // __syncthreads inside blockMaxBcast, before slot post
                __hip_atomic_store(&Ry[(size_t)b * G + g0 + t], ynew,
                                   __ATOMIC_RELAXED, __HIP_MEMORY_SCOPE_AGENT);
        }
        float bmC = blockMaxBcast(ynew, scratch8);
        postSlot(&Slots[(it * 3 + 2) * NB + blk], bmC);
        float m3 = waitMax(&Slots[(it * 3 + 2) * NB], scratch8);
        s3 = (m3 > 1.0f) ? 1.0f / m3 : 1.0f;
    }

    if (t < TILE) out[(size_t)b * G + g0 + t] = s3 * Rreg;
}

extern "C" void kernel_launch(void* const* d_in, const int* in_sizes, int n_in,
                              void* d_out, int out_size, void* d_ws, size_t ws_size,
                              hipStream_t stream) {
    const float* x = (const float*)d_in[0];   // (B,G)
    const float* W = (const float*)d_in[1];   // (M,C)
    const int*   I = (const int*)d_in[2];     // (C,G,S,L)
    float* out = (float*)d_out;

    unsigned* ws    = (unsigned*)d_ws;
    unsigned* Slots = ws;                     // 15 * 256 (poisoned 0xAA by harness)
    float*    Ry    = (float*)(ws + 15 * NB + 64);   // B*G

    // grid(256) == CU count; each CU fits >=2 such blocks (26KB LDS, ~80 VGPR)
    // -> all blocks co-resident by capacity; custom dataflow sync, no coop API.
    fused<<<dim3(NB), dim3(TPB), 0, stream>>>(x, W, I, out, Slots, Ry);
}

// Round 6
// 200.328 us; speedup vs baseline: 1.0484x; 1.0484x over previous
//
#include <hip/hip_runtime.h>

#define GAMMA 0.01f
#define INV_GAMMA 100.0f
#define B 32
#define G 2048
#define C 16
#define S 8
#define L 3
#define M 16
#define NB 256          // 32 b x 8 tiles; == CU count
#define TPB 512
#define TILE 256        // g per block
#define POISON 0xAAAAAAAAu   // harness poisons d_ws; posted maxes are >=0 (sign bit 0)

__device__ __forceinline__ float waveMax(float v) {
#pragma unroll
    for (int off = 32; off > 0; off >>= 1)
        v = fmaxf(v, __shfl_xor(v, off, 64));
    return v;
}

// 512-thread block max, broadcast. Leading guard sync makes repeated use safe.
__device__ __forceinline__ float blockMaxBcast(float v, float* scratch8) {
    float wm = waveMax(v);
    __syncthreads();
    if ((threadIdx.x & 63) == 0) scratch8[threadIdx.x >> 6] = wm;
    __syncthreads();
    float r = fmaxf(fmaxf(scratch8[0], scratch8[1]), fmaxf(scratch8[2], scratch8[3]));
    return fmaxf(r, fmaxf(fmaxf(scratch8[4], scratch8[5]), fmaxf(scratch8[6], scratch8[7])));
}

__device__ __forceinline__ void postSlot(unsigned* slot, float bm) {
    if (threadIdx.x == 0)   // release: vmcnt(0) drain orders prior Ry stores first
        __hip_atomic_store(slot, __float_as_uint(bm),
                           __ATOMIC_RELEASE, __HIP_MEMORY_SCOPE_AGENT);
}

// 2-hop barrier tail: wave 7 (threads 448..511) polls all NB slots, 4 per lane
// (coalesced, 16 lines/round), wave-reduces, LDS-broadcasts. Other waves just
// hit the __syncthreads (caller may overlap work on them before calling).
__device__ __forceinline__ float waitSlots(const unsigned* __restrict__ slots,
                                           float* bcast) {
    const int t = threadIdx.x;
    if (t >= TPB - 64) {
        const int l = t - (TPB - 64);
        unsigned u0, u1, u2, u3;
        for (;;) {
            u0 = __hip_atomic_load(&slots[l],       __ATOMIC_RELAXED, __HIP_MEMORY_SCOPE_AGENT);
            u1 = __hip_atomic_load(&slots[l + 64],  __ATOMIC_RELAXED, __HIP_MEMORY_SCOPE_AGENT);
            u2 = __hip_atomic_load(&slots[l + 128], __ATOMIC_RELAXED, __HIP_MEMORY_SCOPE_AGENT);
            u3 = __hip_atomic_load(&slots[l + 192], __ATOMIC_RELAXED, __HIP_MEMORY_SCOPE_AGENT);
            if (u0 != POISON && u1 != POISON && u2 != POISON && u3 != POISON) break;
            __builtin_amdgcn_s_sleep(1);
        }
        float v = fmaxf(fmaxf(__uint_as_float(u0), __uint_as_float(u1)),
                        fmaxf(__uint_as_float(u2), __uint_as_float(u3)));
        v = waveMax(v);
        if (l == 0) *bcast = v;
    }
    __syncthreads();
    return *bcast;
}

__global__ __launch_bounds__(TPB, 1) void fused(
    const float* __restrict__ x, const float* __restrict__ W,
    const int* __restrict__ I, float* __restrict__ out,
    unsigned* __restrict__ Slots, float* __restrict__ Ry) {
    __shared__ float Vrow[G];        // 8 KB
    __shared__ float CvL[C][TILE];   // 16 KB, block-local Cv tile
    __shared__ float WsL[M * C];     // 1 KB
    __shared__ float scratch8[8];
    __shared__ float bcast;

    const int t   = threadIdx.x;
    const int blk = blockIdx.x;
    const int b   = blk >> 3;
    const int g0  = (blk & 7) * TILE;

    // Ws = softmax(W, axis=1), redundant per block. First read is after the
    // syncs inside phase A's blockMaxBcast.
    if (t < M * C) {
        int m = t >> 4, c = t & 15;
        float rmax = -INFINITY;
#pragma unroll
        for (int j = 0; j < C; j++) rmax = fmaxf(rmax, W[m * C + j]);
        float rsum = 0.f;
#pragma unroll
        for (int j = 0; j < C; j++) rsum += __expf(W[m * C + j] - rmax);
        WsL[t] = __expf(W[m * C + c] - rmax) / rsum;
    }

    float Rreg = (t < TILE) ? x[(size_t)b * G + g0 + t] : 0.f;  // unscaled y
    float s3 = 1.0f;

    for (int it = 0; it < 5; ++it) {
        // ---- stage V row b into LDS (scaled by s3) ----
        if (it == 0) {
            ((float4*)Vrow)[t] = ((const float4*)(x + (size_t)b * G))[t];  // 8 KB
        } else {
            // agent loads bypass stale per-XCD L2; producers stored agent-scope
            // and drained (release post) before we could observe their slot C.
#pragma unroll
            for (int k = 0; k < 4; k++) {
                int j = t + k * TPB;
                float v = __hip_atomic_load(&Ry[(size_t)b * G + j],
                                            __ATOMIC_RELAXED, __HIP_MEMORY_SCOPE_AGENT);
                Vrow[j] = s3 * v;
            }
        }
        __syncthreads();

        // ---- Phase A: Cv tile = softor_S(prod_L gather(V)) ----
        const int gl = t & 255;
        const int cb = (t >> 8) * 8;
        float ymax = -INFINITY;
#pragma unroll 2
        for (int cc = 0; cc < 8; cc++) {
            const int c = cb + cc;
            const int4* ip = (const int4*)(I + ((size_t)c * G + g0 + gl) * (S * L));
            int idx[S * L];
#pragma unroll
            for (int q = 0; q < 6; q++) {
                int4 v = ip[q];
                idx[q * 4 + 0] = v.x; idx[q * 4 + 1] = v.y;
                idx[q * 4 + 2] = v.z; idx[q * 4 + 3] = v.w;
            }
            float body[S];
#pragma unroll
            for (int ss = 0; ss < S; ss++)
                body[ss] = Vrow[idx[ss * 3]] * Vrow[idx[ss * 3 + 1]] * Vrow[idx[ss * 3 + 2]];
            float bm = body[0];
#pragma unroll
            for (int ss = 1; ss < S; ss++) bm = fmaxf(bm, body[ss]);
            float sum = 0.f;
#pragma unroll
            for (int ss = 0; ss < S; ss++) sum += __expf((body[ss] - bm) * INV_GAMMA);
            float y = bm + GAMMA * __logf(sum);
            CvL[c][gl] = y;
            ymax = fmaxf(ymax, y);
        }
        float bmA = blockMaxBcast(ymax, scratch8);   // also publishes CvL
        postSlot(&Slots[(it * 3 + 0) * NB + blk], bmA);

        // ---- Phase B part 1 (overlaps barrier A): Hraw = Ws @ Cv ----
        // Linear in Cv -> needs no s1. Wave 7 polls meanwhile; waves 4-6 wait.
        float Hraw[M], hmr = -INFINITY;
        if (t < TILE) {
            float cv[C];
#pragma unroll
            for (int c = 0; c < C; c++) cv[c] = CvL[c][t];
#pragma unroll
            for (int m = 0; m < M; m++) {
                float acc = 0.f;
#pragma unroll
                for (int c = 0; c < C; c++) acc = fmaf(WsL[m * C + c], cv[c], acc);
                Hraw[m] = acc; hmr = fmaxf(hmr, acc);
            }
        }
        float m1 = waitSlots(&Slots[(it * 3 + 0) * NB], &bcast);
        float s1 = (m1 > 1.0f) ? 1.0f / m1 : 1.0f;

        // ---- Phase B part 2: Hy = softor_M(s1 * Hraw) ----
        float hy = -INFINITY;
        if (t < TILE) {
            float hm = s1 * hmr;           // s1 > 0: max commutes with scaling
            float sum = 0.f;
#pragma unroll
            for (int m = 0; m < M; m++)
                sum += __expf((s1 * Hraw[m] - hm) * INV_GAMMA);
            hy = hm + GAMMA * __logf(sum);
        }
        float bmB = blockMaxBcast(hy, scratch8);
        postSlot(&Slots[(it * 3 + 1) * NB + blk], bmB);
        float m2 = waitSlots(&Slots[(it * 3 + 1) * NB], &bcast);
        float s2 = (m2 > 1.0f) ? 1.0f / m2 : 1.0f;

        // ---- Phase C: R_new = softor_2(s3*R, s2*Hy) ----
        float ynew = -INFINITY;
        if (t < TILE) {
            float Rv = s3 * Rreg;
            float rv = s2 * hy;
            float a = fmaxf(Rv, rv), d = fminf(Rv, rv);
            ynew = a + GAMMA * __logf(1.0f + __expf((d - a) * INV_GAMMA));
            Rreg = ynew;
            if (it < 4)   // agent store -> LLC; drained by the release in postSlot
                __hip_atomic_store(&Ry[(size_t)b * G + g0 + t], ynew,
                                   __ATOMIC_RELAXED, __HIP_MEMORY_SCOPE_AGENT);
        }
        float bmC = blockMaxBcast(ynew, scratch8);
        postSlot(&Slots[(it * 3 + 2) * NB + blk], bmC);
        float m3 = waitSlots(&Slots[(it * 3 + 2) * NB], &bcast);
        s3 = (m3 > 1.0f) ? 1.0f / m3 : 1.0f;
    }

    if (t < TILE) out[(size_t)b * G + g0 + t] = s3 * Rreg;
}

extern "C" void kernel_launch(void* const* d_in, const int* in_sizes, int n_in,
                              void* d_out, int out_size, void* d_ws, size_t ws_size,
                              hipStream_t stream) {
    const float* x = (const float*)d_in[0];   // (B,G)
    const float* W = (const float*)d_in[1];   // (M,C)
    const int*   I = (const int*)d_in[2];     // (C,G,S,L)
    float* out = (float*)d_out;

    unsigned* ws    = (unsigned*)d_ws;
    unsigned* Slots = ws;                     // 15 * 256 (poisoned 0xAA by harness)
    float*    Ry    = (float*)(ws + 15 * NB + 64);   // B*G

    // grid(256) == CU count; ~3 blocks/CU capacity (26KB LDS, 68 VGPR) ->
    // all blocks co-resident; dataflow sync via slot polling, no coop API.
    fused<<<dim3(NB), dim3(TPB), 0, stream>>>(x, W, I, out, Slots, Ry);
}